// Round 4
// baseline (190.886 us; speedup 1.0000x reference)
//
#include <hip/hip_runtime.h>
#include <math.h>

#define NB    128
#define NG    52
#define NGG   2704          // NG*NG
#define NA    3
#define NCLS  15
#define NCH   20
#define NQ    8112          // NA*NGG
#define TOTAL 1038336       // NB*NQ
#define CPT   4             // cells per thread
#define NTHREADS (TOTAL/CPT)   // 259584
#define BLK   64               // single-wave blocks
#define NBLK  (NTHREADS/BLK)   // 4056 (exact)
#define NPART NBLK

__device__ __forceinline__ float sigmoidf(float z) { return 1.0f / (1.0f + expf(-z)); }

template<int J>
__device__ __forceinline__ float getc(const float4& v) {
    if constexpr (J == 0) return v.x;
    else if constexpr (J == 1) return v.y;
    else if constexpr (J == 2) return v.z;
    else return v.w;
}

// transform cell J of the 4-cell float4 bundle; returns conf, fills c[20]
template<int J>
__device__ __forceinline__ float transform(const float4* __restrict__ z, float* __restrict__ c) {
    c[0] = 8.0f * sigmoidf(getc<J>(z[0]));
    c[1] = 8.0f * sigmoidf(getc<J>(z[1]));
    c[2] = 8.0f * getc<J>(z[2]);
    c[3] = 8.0f * getc<J>(z[3]);
    float conf = sigmoidf(getc<J>(z[4]));
    c[4] = conf;
    float s = 0.0f;
    #pragma unroll
    for (int cc = 0; cc < NCLS; cc++) { c[5+cc] = expf(getc<J>(z[5+cc])); s += c[5+cc]; }
    float inv = 1.0f / s;
    #pragma unroll
    for (int cc = 0; cc < NCLS; cc++) c[5+cc] *= inv;
    return conf;
}

// ---- main kernel: 4 cells/thread, float4 loads, incremental float4 stores ----
__global__ __launch_bounds__(BLK) void main_kernel(const float* __restrict__ x,
                                                   float* __restrict__ out,
                                                   float* __restrict__ partials) {
    int t = threadIdx.x;
    int T = blockIdx.x * BLK + t;      // thread handles cells 4T..4T+3
    int cell0 = T * CPT;
    int b  = cell0 / NQ;
    int r  = cell0 - b * NQ;
    int a  = r / NGG;
    int ji = r - a * NGG;              // multiple of 4; all 4 cells in same plane

    const float4* __restrict__ xp =
        (const float4*)(x + ((size_t)(b*60 + a*20)) * NGG) + (ji >> 2);

    float4 z[NCH];
    #pragma unroll
    for (int c = 0; c < NCH; c++) z[c] = xp[c * (NGG/4)];

    size_t W = 4 + (size_t)T * 80;     // aligned window [W, W+80) in out floats
    float4* __restrict__ op = (float4*)(out + W);

    float tsum;
    float va0, va1, va2;               // cell0 ch0-2 (shfl'd to lane-1 / stored by T==0)
    float carry;

    {   // cells 0,1 -> quads 0..8
        float c0[NCH], c1[NCH];
        float cf0 = transform<0>(z, c0);
        float cf1 = transform<1>(z, c1);
        tsum  = -fmaxf(logf(1.0f - cf0), -100.0f);
        tsum += -fmaxf(logf(1.0f - cf1), -100.0f);
        va0 = c0[0]; va1 = c0[1]; va2 = c0[2];
        op[0] = make_float4(c0[3],  c0[4],  c0[5],  c0[6]);
        op[1] = make_float4(c0[7],  c0[8],  c0[9],  c0[10]);
        op[2] = make_float4(c0[11], c0[12], c0[13], c0[14]);
        op[3] = make_float4(c0[15], c0[16], c0[17], c0[18]);
        op[4] = make_float4(c0[19], c1[0],  c1[1],  c1[2]);
        op[5] = make_float4(c1[3],  c1[4],  c1[5],  c1[6]);
        op[6] = make_float4(c1[7],  c1[8],  c1[9],  c1[10]);
        op[7] = make_float4(c1[11], c1[12], c1[13], c1[14]);
        op[8] = make_float4(c1[15], c1[16], c1[17], c1[18]);
        carry = c1[19];
    }
    {   // cell 2 -> quads 9..13
        float c2[NCH];
        float cf2 = transform<2>(z, c2);
        tsum += -fmaxf(logf(1.0f - cf2), -100.0f);
        op[9]  = make_float4(carry,  c2[0],  c2[1],  c2[2]);
        op[10] = make_float4(c2[3],  c2[4],  c2[5],  c2[6]);
        op[11] = make_float4(c2[7],  c2[8],  c2[9],  c2[10]);
        op[12] = make_float4(c2[11], c2[12], c2[13], c2[14]);
        op[13] = make_float4(c2[15], c2[16], c2[17], c2[18]);
        carry = c2[19];
    }
    {   // cell 3 -> quads 14..18
        float c3[NCH];
        float cf3 = transform<3>(z, c3);
        tsum += -fmaxf(logf(1.0f - cf3), -100.0f);
        op[14] = make_float4(carry,  c3[0],  c3[1],  c3[2]);
        op[15] = make_float4(c3[3],  c3[4],  c3[5],  c3[6]);
        op[16] = make_float4(c3[7],  c3[8],  c3[9],  c3[10]);
        op[17] = make_float4(c3[11], c3[12], c3[13], c3[14]);
        op[18] = make_float4(c3[15], c3[16], c3[17], c3[18]);
        carry = c3[19];
    }

    // quad 19: carry + next cell's (4T+4) ch0-2 from lane+1
    float n0 = __shfl_down(va0, 1, 64);
    float n1 = __shfl_down(va1, 1, 64);
    float n2 = __shfl_down(va2, 1, 64);
    if (t == 63 && cell0 + 4 < TOTAL) {
        int c2i = cell0 + 4;
        int b2  = c2i / NQ;
        int r2  = c2i - b2 * NQ;
        int a2  = r2 / NGG;
        int ji2 = r2 - a2 * NGG;
        const float* q = x + ((size_t)(b2*60 + a2*20)) * NGG + ji2;
        n0 = 8.0f * sigmoidf(q[0]);
        n1 = 8.0f * sigmoidf(q[(size_t)NGG]);
        n2 = 8.0f * q[(size_t)2*NGG];
    }
    if (T != NTHREADS - 1) {
        op[19] = make_float4(carry, n0, n1, n2);
    } else {
        out[W + 76] = carry;               // last valid out float
    }
    if (T == 0) { out[1] = va0; out[2] = va1; out[3] = va2; }

    // per-wave noobj partial
    #pragma unroll
    for (int off = 32; off > 0; off >>= 1) tsum += __shfl_down(tsum, off, 64);
    if (t == 0) partials[blockIdx.x] = tsum;
}

// ---------------- finish: partial sum + per-batch corrections + loss ------
__global__ void finish_kernel(const float* __restrict__ labels,
                              const float* __restrict__ partials,
                              float* __restrict__ out) {
    int t = threadIdx.x;   // 256 threads
    float s = 0.0f;
    for (int q = t; q < NPART; q += 256) s += partials[q];

    float corr_part = 0.0f;
    if (t < NB) {
        int b = t;
        float gx = labels[b*5+0] * (float)NG;
        float gy = labels[b*5+1] * (float)NG;
        float gw = labels[b*5+2] * (float)NG;
        float gh = labels[b*5+3] * (float)NG;
        int gcls = (int)labels[b*5+4];
        int gi = (int)gx, gj = (int)gy;
        const float aw[3] = {12.0f, 9.875f, 10.125f};
        const float ah[3] = {28.75f, 23.25f, 16.625f};
        float iou[3];
        #pragma unroll
        for (int a = 0; a < 3; a++) {
            float inter = fminf(aw[a], gw) * fminf(ah[a], gh);
            iou[a] = inter / (aw[a]*ah[a] + 1e-16f + gw*gh - inter);
        }
        int best = 0; float bv = iou[0];
        if (iou[1] > bv) { best = 1; bv = iou[1]; }
        if (iou[2] > bv) { best = 2; bv = iou[2]; }
        float txv = gx - (float)gi;
        float tyv = gy - (float)gj;
        float twv = logf(gw / aw[best] + 1e-16f);
        float thv = logf(gh / ah[best] + 1e-16f);

        float corr = 0.0f;
        #pragma unroll
        for (int a = 0; a < 3; a++) {
            int q = a*NGG + gj*NG + gi;
            const float* ob = out + 1 + ((size_t)b*NQ + q) * NCH;
            float conf = ob[4];
            bool isbest = (a == best);
            if (isbest || iou[a] > 0.5f) {
                corr += -fmaxf(logf(1.0f - conf), -100.0f);   // noobj==0 here: remove
            }
            if (isbest) {
                corr_part += -fmaxf(logf(conf), -100.0f);     // obj conf BCE (t=1)
                float px = ob[0]*0.125f, py = ob[1]*0.125f;
                float pw = ob[2]*0.125f, ph = ob[3]*0.125f;
                corr_part += fabsf(px - txv) + fabsf(py - tyv)
                           + fabsf(pw - twv) + fabsf(ph - thv);
                for (int c = 0; c < NCLS; c++) {
                    float p = ob[5 + c];
                    if (c == gcls) corr_part += -fmaxf(logf(p),        -100.0f);
                    else           corr_part += -fmaxf(logf(1.0f - p), -100.0f);
                }
            }
        }
        corr_part -= 100.0f * corr;
    }

    __shared__ float red[256];
    red[t] = 100.0f * s + corr_part;
    __syncthreads();
    for (int s2 = 128; s2 > 0; s2 >>= 1) {
        if (t < s2) red[t] += red[t + s2];
        __syncthreads();
    }
    if (t == 0) out[0] = red[0];
}

extern "C" void kernel_launch(void* const* d_in, const int* in_sizes, int n_in,
                              void* d_out, int out_size, void* d_ws, size_t ws_size,
                              hipStream_t stream) {
    const float* x      = (const float*)d_in[0];
    const float* labels = (const float*)d_in[1];
    float* out = (float*)d_out;
    float* ws  = (float*)d_ws;

    hipLaunchKernelGGL(main_kernel,   dim3(NBLK), dim3(BLK), 0, stream, x, out, ws);
    hipLaunchKernelGGL(finish_kernel, dim3(1),    dim3(256), 0, stream, labels, ws, out);
}

// Round 5
// 171.134 us; speedup vs baseline: 1.1154x; 1.1154x over previous
//
#include <hip/hip_runtime.h>
#include <math.h>

#define NB    128
#define NG    52
#define NGG   2704          // NG*NG
#define NA    3
#define NCLS  15
#define NCH   20
#define NQ    8112          // NA*NGG
#define TOTAL 1038336       // NB*NQ
#define BLK   256
#define NBLK  (TOTAL/BLK)   // 4056 (exact), 1 cell per thread
#define FPB   (BLK*NCH)     // 5120 out floats per block
#define NQUAD ((FPB-4)/4)   // 1279 aligned float4 stores per block
#define STRIDE 21           // padded LDS cell stride (21 coprime 32 -> conflict-free)
#define NPART (NBLK*4)      // per-wave partials

__device__ __forceinline__ float fsig(float z) {
    return __builtin_amdgcn_rcpf(1.0f + __expf(-z));
}

// ---- main kernel: coalesced loads -> transform -> LDS transpose -> float4 stores ----
__global__ __launch_bounds__(BLK) void main_kernel(const float* __restrict__ x,
                                                   float* __restrict__ out,
                                                   float* __restrict__ partials) {
    __shared__ float sm[BLK * STRIDE];   // 21504 B

    int t = threadIdx.x;
    int cell = blockIdx.x * BLK + t;
    int b  = cell / NQ;
    int r  = cell - b * NQ;
    int a  = r / NGG;
    int ji = r - a * NGG;

    const float* __restrict__ xp = x + ((size_t)(b*60 + a*20)) * NGG + ji;
    float z[NCH];
    #pragma unroll
    for (int c = 0; c < NCH; c++) z[c] = xp[(size_t)c * NGG];

    float conf = fsig(z[4]);
    float v0 = 8.0f * fsig(z[0]);
    float v1 = 8.0f * fsig(z[1]);
    float v2 = 8.0f * z[2];
    float v3 = 8.0f * z[3];

    float e[NCLS]; float s = 0.0f;
    #pragma unroll
    for (int c = 0; c < NCLS; c++) { e[c] = __expf(z[5+c]); s += e[c]; }
    float inv = __builtin_amdgcn_rcpf(s);

    float* row = sm + t * STRIDE;
    row[0] = v0; row[1] = v1; row[2] = v2; row[3] = v3; row[4] = conf;
    #pragma unroll
    for (int c = 0; c < NCLS; c++) row[5 + c] = e[c] * inv;

    // per-wave noobj BCE partial (no barrier needed; independent of LDS phase)
    float tsum = -fmaxf(__logf(1.0f - conf), -100.0f);
    #pragma unroll
    for (int off = 32; off > 0; off >>= 1) tsum += __shfl_down(tsum, off, 64);
    if ((t & 63) == 0) partials[blockIdx.x * 4 + (t >> 6)] = tsum;

    __syncthreads();

    // contiguous float4 stores of the block's out region (window shifted +3 for alignment)
    size_t gbase = (size_t)blockIdx.x * FPB;   // out[0] is the loss slot
    float4* __restrict__ op = (float4*)(out + gbase + 4);
    #pragma unroll
    for (int k = 0; k < 5; k++) {
        int q = k * BLK + t;
        if (q < NQUAD) {
            int f  = 4*q + 3;              // flat payload pos within block
            int cl = f / 20;
            int cc = f - cl * 20;
            float r0 = sm[cl*STRIDE + cc];
            cc++; if (cc == 20) { cc = 0; cl++; }
            float r1 = sm[cl*STRIDE + cc];
            cc++; if (cc == 20) { cc = 0; cl++; }
            float r2 = sm[cl*STRIDE + cc];
            cc++; if (cc == 20) { cc = 0; cl++; }
            float r3 = sm[cl*STRIDE + cc];
            op[q] = make_float4(r0, r1, r2, r3);
        }
    }
    if (t == 0) {
        out[gbase + 1]   = sm[0];                  // cell0 ch0
        out[gbase + 2]   = sm[1];                  // cell0 ch1
        out[gbase + 3]   = sm[2];                  // cell0 ch2
        out[gbase + FPB] = sm[255*STRIDE + 19];    // cell255 ch19
    }
}

// ---------------- finish: partial sum + per-batch corrections + loss ------
__global__ void finish_kernel(const float* __restrict__ labels,
                              const float* __restrict__ partials,
                              float* __restrict__ out) {
    int t = threadIdx.x;   // 256 threads
    float s = 0.0f;
    for (int q = t; q < NPART; q += 256) s += partials[q];

    float corr_part = 0.0f;
    if (t < NB) {
        int b = t;
        float gx = labels[b*5+0] * (float)NG;
        float gy = labels[b*5+1] * (float)NG;
        float gw = labels[b*5+2] * (float)NG;
        float gh = labels[b*5+3] * (float)NG;
        int gcls = (int)labels[b*5+4];
        int gi = (int)gx, gj = (int)gy;
        const float aw[3] = {12.0f, 9.875f, 10.125f};
        const float ah[3] = {28.75f, 23.25f, 16.625f};
        float iou[3];
        #pragma unroll
        for (int a = 0; a < 3; a++) {
            float inter = fminf(aw[a], gw) * fminf(ah[a], gh);
            iou[a] = inter / (aw[a]*ah[a] + 1e-16f + gw*gh - inter);
        }
        int best = 0; float bv = iou[0];
        if (iou[1] > bv) { best = 1; bv = iou[1]; }
        if (iou[2] > bv) { best = 2; bv = iou[2]; }
        float txv = gx - (float)gi;
        float tyv = gy - (float)gj;
        float twv = logf(gw / aw[best] + 1e-16f);
        float thv = logf(gh / ah[best] + 1e-16f);

        float corr = 0.0f;
        #pragma unroll
        for (int a = 0; a < 3; a++) {
            int q = a*NGG + gj*NG + gi;
            const float* ob = out + 1 + ((size_t)b*NQ + q) * NCH;
            float conf = ob[4];
            bool isbest = (a == best);
            if (isbest || iou[a] > 0.5f) {
                corr += -fmaxf(logf(1.0f - conf), -100.0f);   // noobj==0 here: remove
            }
            if (isbest) {
                corr_part += -fmaxf(logf(conf), -100.0f);     // obj conf BCE (t=1)
                float px = ob[0]*0.125f, py = ob[1]*0.125f;
                float pw = ob[2]*0.125f, ph = ob[3]*0.125f;
                corr_part += fabsf(px - txv) + fabsf(py - tyv)
                           + fabsf(pw - twv) + fabsf(ph - thv);
                for (int c = 0; c < NCLS; c++) {
                    float p = ob[5 + c];
                    if (c == gcls) corr_part += -fmaxf(logf(p),        -100.0f);
                    else           corr_part += -fmaxf(logf(1.0f - p), -100.0f);
                }
            }
        }
        corr_part -= 100.0f * corr;
    }

    __shared__ float red[256];
    red[t] = 100.0f * s + corr_part;
    __syncthreads();
    for (int s2 = 128; s2 > 0; s2 >>= 1) {
        if (t < s2) red[t] += red[t + s2];
        __syncthreads();
    }
    if (t == 0) out[0] = red[0];
}

extern "C" void kernel_launch(void* const* d_in, const int* in_sizes, int n_in,
                              void* d_out, int out_size, void* d_ws, size_t ws_size,
                              hipStream_t stream) {
    const float* x      = (const float*)d_in[0];
    const float* labels = (const float*)d_in[1];
    float* out = (float*)d_out;
    float* ws  = (float*)d_ws;

    hipLaunchKernelGGL(main_kernel,   dim3(NBLK), dim3(BLK), 0, stream, x, out, ws);
    hipLaunchKernelGGL(finish_kernel, dim3(1),    dim3(256), 0, stream, labels, ws, out);
}